// Round 1
// baseline (826.336 us; speedup 1.0000x reference)
//
#include <hip/hip_runtime.h>
#include <hip/hip_bf16.h>
#include <math.h>

// Problem constants
#define BQ 512
#define DIM 512
#define NMEM 131072
#define TOPK 16

// Tiling
#define BM 128                   // query rows per block
#define BN 128                   // memory rows per subtile
#define BK 32                    // k per stage (one MFMA-K)
#define KSTEPS (DIM / BK)        // 16
#define NSUB 8
#define CHUNK_N (BN * NSUB)      // 1024 memory rows per block
#define CHUNKS (NMEM / CHUNK_N)  // 128
#define BTILES (BQ / BM)         // 4
#define CAP 32                   // candidate buffer per row (fallback kernel)
#define CAPF 24                  // candidate buffer per row (fast kernel, fits 2 blocks/CU)
#define RESCORE 32               // global candidates rescored in fp32
#define LDSTR 40                 // LDS row stride in ushorts (fallback kernel)
#define NEG_INF (-3.402823466e38f)

typedef unsigned short u16;
typedef unsigned int u32;
typedef short bf16x8 __attribute__((ext_vector_type(8)));
typedef float f32x4 __attribute__((ext_vector_type(4)));

static __device__ inline u32 pack2(float a, float b) {
  __hip_bfloat162 p = __float22bfloat162_rn(make_float2(a, b));
  return *(u32*)&p;
}

// 16B async global->LDS. LDS dest must be wave-uniform base; lane l lands at
// base + l*16. Global source is per-lane (this is how we pre-swizzle).
static __device__ inline void gl_lds16(const void* g, void* l) {
  __builtin_amdgcn_global_load_lds(
      (const __attribute__((address_space(1))) u32*)g,
      (__attribute__((address_space(3))) u32*)l, 16, 0, 0);
}

// ---------------------------------------------------------------------------
// prep: inv_qn[b] = 1/||q_b|| (fp32 exact) + query converted to bf16
__global__ __launch_bounds__(256) void prep_kernel(const float* __restrict__ q,
                                                   float* __restrict__ inv_qn,
                                                   u16* __restrict__ qb) {
  int row = blockIdx.x * 4 + (threadIdx.x >> 6);
  int lane = threadIdx.x & 63;
  const float4* r4 = (const float4*)(q + (size_t)row * DIM);
  float4 x0 = r4[lane * 2], x1 = r4[lane * 2 + 1];
  float ss = x0.x * x0.x + x0.y * x0.y + x0.z * x0.z + x0.w * x0.w +
             x1.x * x1.x + x1.y * x1.y + x1.z * x1.z + x1.w * x1.w;
#pragma unroll
  for (int off = 32; off; off >>= 1) ss += __shfl_down(ss, off);
  if (lane == 0) inv_qn[row] = 1.0f / sqrtf(ss);
  uint4 w;
  w.x = pack2(x0.x, x0.y);
  w.y = pack2(x0.z, x0.w);
  w.z = pack2(x1.x, x1.y);
  w.w = pack2(x1.z, x1.w);
  *(uint4*)(qb + (size_t)row * DIM + lane * 8) = w;
}

// ---------------------------------------------------------------------------
// convert: one-shot fp32->bf16 copy of memory_matrix + fused column scale
// colscale[n] = (1 + 0.3*imp[n]) / ||m_n||  (norm in exact fp32).
// One wave per row: 64 lanes x 8 floats = 512. ~384 MB traffic total.
__global__ __launch_bounds__(256) void convert_kernel(
    const float* __restrict__ mem, const float* __restrict__ imp,
    u16* __restrict__ membf, float* __restrict__ colscale) {
  int row = blockIdx.x * 4 + (threadIdx.x >> 6);
  int lane = threadIdx.x & 63;
  const float4* r4 = (const float4*)(mem + (size_t)row * DIM);
  float4 x0 = r4[lane * 2], x1 = r4[lane * 2 + 1];
  float ss = x0.x * x0.x + x0.y * x0.y + x0.z * x0.z + x0.w * x0.w +
             x1.x * x1.x + x1.y * x1.y + x1.z * x1.z + x1.w * x1.w;
  uint4 w;
  w.x = pack2(x0.x, x0.y);
  w.y = pack2(x0.z, x0.w);
  w.z = pack2(x1.x, x1.y);
  w.w = pack2(x1.z, x1.w);
  *(uint4*)(membf + (size_t)row * DIM + lane * 8) = w;
#pragma unroll
  for (int off = 32; off; off >>= 1) ss += __shfl_down(ss, off);
  if (lane == 0) colscale[row] = (1.0f + 0.3f * imp[row]) / sqrtf(ss);
}

// ---------------------------------------------------------------------------
// fast main: pure bf16 GEMM (global_load_lds double-buffered, 1 barrier/K-step)
// + fused per-row running top-16 per chunk. No per-element conversion, no norm
// work in the hot loop.
//
// Fragment reads use a k-chunk XOR swizzle (kchunk ^= row&3) to cut the
// ds_read_b128 bank conflict from 8-way to 4-way. Per rule #21 the swizzle is
// applied on BOTH sides: the per-lane *global source* address is pre-swizzled
// (LDS write stays linear, as global_load_lds requires) and the ds_read uses
// the same involution.
static __device__ inline void mfma_step(const u16* Asb, const u16* Bsb, int wm,
                                        int wn, int c16, int quad,
                                        f32x4 acc[4][4]) {
  bf16x8 af[4], bfr[4];
  const int ksw = (quad ^ (c16 & 3)) * 8;
#pragma unroll
  for (int mi = 0; mi < 4; ++mi)
    af[mi] = *(const bf16x8*)&Asb[(wm * 64 + mi * 16 + c16) * BK + ksw];
#pragma unroll
  for (int ni = 0; ni < 4; ++ni)
    bfr[ni] = *(const bf16x8*)&Bsb[(wn * 64 + ni * 16 + c16) * BK + ksw];
#pragma unroll
  for (int mi = 0; mi < 4; ++mi)
#pragma unroll
    for (int ni = 0; ni < 4; ++ni)
      acc[mi][ni] = __builtin_amdgcn_mfma_f32_16x16x32_bf16(af[mi], bfr[ni],
                                                            acc[mi][ni], 0, 0, 0);
}

static __device__ inline void stage4(const u16* ag0, const u16* ag1,
                                     const u16* bg0, const u16* bg1, u16* Asb,
                                     u16* Bsb, int blk0, int blk1, int koff) {
  gl_lds16(ag0 + koff, Asb + blk0 * 512);
  gl_lds16(ag1 + koff, Asb + blk1 * 512);
  gl_lds16(bg0 + koff, Bsb + blk0 * 512);
  gl_lds16(bg1 + koff, Bsb + blk1 * 512);
}

__global__ __launch_bounds__(256, 2) void main_fast(
    const u16* __restrict__ qb, const u16* __restrict__ membf,
    const float* __restrict__ cs, const float* __restrict__ inv_qn,
    float* __restrict__ part_v, int* __restrict__ part_i) {
  __shared__ __align__(16) u16 As[2][BM * BK];  // 2 x 8 KB
  __shared__ __align__(16) u16 Bs[2][BN * BK];  // 2 x 8 KB
  __shared__ float topv[BM][TOPK];
  __shared__ int topi[BM][TOPK];
  __shared__ float cbv[BM * CAPF];
  __shared__ int cbi[BM * CAPF];
  __shared__ float cutoff[BM];
  __shared__ int cnt[BM];
  __shared__ float qn_s[BM];
  __shared__ int again;
  // total ~75.3 KB -> 2 blocks/CU

  const int tid = threadIdx.x;
  const int lane = tid & 63, wid = tid >> 6;
  const int wm = wid >> 1, wn = wid & 1;
  const int c16 = lane & 15, quad = lane >> 4;

  // XCD swizzle: 4 blocks sharing a chunk land on the same XCD (lin % 8)
  const int lin = blockIdx.x;
  const int btile = (lin >> 3) & 3;
  const int chunk = (lin & 7) + ((lin >> 5) << 3);
  const int bbase = btile * BM;

  for (int e = tid; e < BM * TOPK; e += 256) {
    topv[e >> 4][e & 15] = NEG_INF;
    topi[e >> 4][e & 15] = -1;
  }
  if (tid < BM) {
    cutoff[tid] = NEG_INF;
    cnt[tid] = 0;
    qn_s[tid] = inv_qn[bbase + tid];
  }
  if (tid == 0) again = 0;
  __syncthreads();

  float qnl[16];
#pragma unroll
  for (int ii = 0; ii < 16; ++ii)
    qnl[ii] = qn_s[wm * 64 + (ii >> 2) * 16 + quad * 4 + (ii & 3)];

  // Staging geometry: wave wid owns 1KB blocks {2*wid, 2*wid+1} of each tile.
  // Block = 16 rows x 32 k. Lane l -> row blk*16 + (l>>2), k-chunk (l&3)*8 in
  // LDS; global source k-chunk is pre-swizzled by row&3 (involution).
  const int blk0 = wid * 2, blk1 = wid * 2 + 1;
  const int rin = lane >> 2;              // row within 16-row block
  const int sr0 = blk0 * 16 + rin;
  const int sr1 = blk1 * 16 + rin;
  const int skof = (((lane & 3) ^ (rin & 3)) * 8);  // pre-swizzled k-chunk
  const u16* ag0 = qb + (size_t)(bbase + sr0) * DIM + skof;
  const u16* ag1 = qb + (size_t)(bbase + sr1) * DIM + skof;

  for (int sub = 0; sub < NSUB; ++sub) {
    const int n0g = chunk * CHUNK_N + sub * BN;
    const u16* bg0 = membf + (size_t)(n0g + sr0) * DIM + skof;
    const u16* bg1 = membf + (size_t)(n0g + sr1) * DIM + skof;

    f32x4 acc[4][4];
#pragma unroll
    for (int mi = 0; mi < 4; ++mi)
#pragma unroll
      for (int ni = 0; ni < 4; ++ni) acc[mi][ni] = (f32x4){0.f, 0.f, 0.f, 0.f};

    // prologue: stage kt=0 into buffer 0
    stage4(ag0, ag1, bg0, bg1, &As[0][0], &Bs[0][0], blk0, blk1, 0);
    __syncthreads();  // vmcnt auto-drained

    for (int kp = 0; kp < KSTEPS / 2; ++kp) {
      // even step: prefetch kt=2kp+1 into buf1, compute buf0
      stage4(ag0, ag1, bg0, bg1, &As[1][0], &Bs[1][0], blk0, blk1,
             (2 * kp + 1) * BK);
      mfma_step(&As[0][0], &Bs[0][0], wm, wn, c16, quad, acc);
      __syncthreads();
      // odd step: prefetch kt=2kp+2 into buf0, compute buf1
      if (kp + 1 < KSTEPS / 2)
        stage4(ag0, ag1, bg0, bg1, &As[0][0], &Bs[0][0], blk0, blk1,
               (2 * kp + 2) * BK);
      mfma_step(&As[1][0], &Bs[1][0], wm, wn, c16, quad, acc);
      __syncthreads();
    }

    // precomputed column scale (norm + importance), L2-resident
    float scl[4];
    int gcol[4];
#pragma unroll
    for (int ni = 0; ni < 4; ++ni) {
      const int c = n0g + wn * 64 + ni * 16 + c16;
      scl[ni] = cs[c];
      gcol[ni] = c;
    }
#pragma unroll
    for (int mi = 0; mi < 4; ++mi)
#pragma unroll
      for (int ni = 0; ni < 4; ++ni)
#pragma unroll
        for (int reg = 0; reg < 4; ++reg)
          acc[mi][ni][reg] *= qnl[mi * 4 + reg] * scl[ni];

    // push/merge retry loop (consumed-bit dedup)
    unsigned long long consumed = 0ull;
    for (;;) {
      float cutl[16];
#pragma unroll
      for (int ii = 0; ii < 16; ++ii)
        cutl[ii] = cutoff[wm * 64 + (ii >> 2) * 16 + quad * 4 + (ii & 3)];
#pragma unroll
      for (int mi = 0; mi < 4; ++mi)
#pragma unroll
        for (int reg = 0; reg < 4; ++reg) {
          const int r = wm * 64 + mi * 16 + quad * 4 + reg;
          const float cl = cutl[mi * 4 + reg];
#pragma unroll
          for (int ni = 0; ni < 4; ++ni) {
            const int bit = mi * 16 + ni * 4 + reg;
            const float v = acc[mi][ni][reg];
            if (!((consumed >> bit) & 1ull) && v > cl) {
              int pos = atomicAdd(&cnt[r], 1);
              if (pos < CAPF) {
                cbv[r * CAPF + pos] = v;
                cbi[r * CAPF + pos] = gcol[ni];
                consumed |= 1ull << bit;
              }
            }
          }
        }
      __syncthreads();
      if (tid < BM) {
        const int r = tid;
        const int m = cnt[r];
        const int take = m < CAPF ? m : CAPF;
        for (int c = 0; c < take; ++c) {
          const float v = cbv[r * CAPF + c];
          const int id = cbi[r * CAPF + c];
          if (v > topv[r][TOPK - 1]) {
            int j = TOPK - 1;
            while (j > 0 && topv[r][j - 1] < v) {
              topv[r][j] = topv[r][j - 1];
              topi[r][j] = topi[r][j - 1];
              --j;
            }
            topv[r][j] = v;
            topi[r][j] = id;
          }
        }
        cutoff[r] = topv[r][TOPK - 1];
        if (m > CAPF) again = 1;
        cnt[r] = 0;
      }
      __syncthreads();
      const int more = again;
      __syncthreads();
      if (tid == 0) again = 0;
      if (!more) break;
    }
  }

  for (int e = tid; e < BM * TOPK; e += 256) {
    const int r = e >> 4, j = e & 15;
    const size_t o = ((size_t)(bbase + r) * CHUNKS + chunk) * TOPK + j;
    part_v[o] = topv[r][j];
    part_i[o] = topi[r][j];
  }
}

// ---------------------------------------------------------------------------
// fallback main (previous verified kernel, used only if workspace too small
// for the bf16 memory copy): reg-staged fp32->bf16 conversion in the loop.
__global__ __launch_bounds__(256, 2) void main_kernel(
    const u16* __restrict__ qb, const float* __restrict__ mem,
    const float* __restrict__ imp, const float* __restrict__ inv_qn,
    float* __restrict__ part_v, int* __restrict__ part_i) {
  __shared__ __align__(16) u16 As[BM * LDSTR];
  __shared__ __align__(16) u16 Bs[BN * LDSTR];
  __shared__ float topv[BM][TOPK];
  __shared__ int topi[BM][TOPK];
  __shared__ float cbv[BM * CAP];
  __shared__ int cbi[BM * CAP];
  __shared__ float cutoff[BM];
  __shared__ int cnt[BM];
  __shared__ float qn_s[BM];
  __shared__ float msum[BM * 4];
  __shared__ float colscale[BN];
  __shared__ int again;

  const int tid = threadIdx.x;
  const int lane = tid & 63, wid = tid >> 6;
  const int wm = wid >> 1, wn = wid & 1;
  const int c16 = lane & 15, quad = lane >> 4;

  const int lin = blockIdx.x;
  const int btile = (lin >> 3) & 3;
  const int chunk = (lin & 7) + ((lin >> 5) << 3);
  const int bbase = btile * BM;

  for (int e = tid; e < BM * TOPK; e += 256) {
    topv[e >> 4][e & 15] = NEG_INF;
    topi[e >> 4][e & 15] = -1;
  }
  if (tid < BM) {
    cutoff[tid] = NEG_INF;
    cnt[tid] = 0;
    qn_s[tid] = inv_qn[bbase + tid];
  }
  if (tid == 0) again = 0;
  __syncthreads();

  float qnl[16];
#pragma unroll
  for (int ii = 0; ii < 16; ++ii)
    qnl[ii] = qn_s[wm * 64 + (ii >> 2) * 16 + quad * 4 + (ii & 3)];

  const int arow = tid >> 2, akc = tid & 3;
  const u16* qsrc0 = qb + (size_t)(bbase + arow) * DIM + akc * 8;
  const u16* qsrc1 = qsrc0 + (size_t)64 * DIM;
  u16* adst0 = As + arow * LDSTR + akc * 8;
  u16* adst1 = adst0 + 64 * LDSTR;
  u16* bdst0 = Bs + arow * LDSTR + akc * 8;
  u16* bdst1 = bdst0 + 64 * LDSTR;

  for (int sub = 0; sub < NSUB; ++sub) {
    const int n0g = chunk * CHUNK_N + sub * BN;
    const float* bsrc0 = mem + (size_t)(n0g + arow) * DIM + akc * 8;
    const float* bsrc1 = bsrc0 + (size_t)64 * DIM;

    f32x4 acc[4][4];
#pragma unroll
    for (int mi = 0; mi < 4; ++mi)
#pragma unroll
      for (int ni = 0; ni < 4; ++ni) acc[mi][ni] = (f32x4){0.f, 0.f, 0.f, 0.f};
    float ss0 = 0.f, ss1 = 0.f;

    for (int kt = 0; kt < DIM / BK; ++kt) {
      const int k0 = kt * BK;
      uint4 qa0 = *(const uint4*)(qsrc0 + k0);
      uint4 qa1 = *(const uint4*)(qsrc1 + k0);
      float4 b0a = *(const float4*)(bsrc0 + k0);
      float4 b0b = *(const float4*)(bsrc0 + k0 + 4);
      float4 b1a = *(const float4*)(bsrc1 + k0);
      float4 b1b = *(const float4*)(bsrc1 + k0 + 4);
      ss0 += b0a.x * b0a.x + b0a.y * b0a.y + b0a.z * b0a.z + b0a.w * b0a.w +
             b0b.x * b0b.x + b0b.y * b0b.y + b0b.z * b0b.z + b0b.w * b0b.w;
      ss1 += b1a.x * b1a.x + b1a.y * b1a.y + b1a.z * b1a.z + b1a.w * b1a.w +
             b1b.x * b1b.x + b1b.y * b1b.y + b1b.z * b1b.z + b1b.w * b1b.w;
      __syncthreads();
      *(uint4*)adst0 = qa0;
      *(uint4*)adst1 = qa1;
      uint4 w0, w1;
      w0.x = pack2(b0a.x, b0a.y); w0.y = pack2(b0a.z, b0a.w);
      w0.z = pack2(b0b.x, b0b.y); w0.w = pack2(b0b.z, b0b.w);
      w1.x = pack2(b1a.x, b1a.y); w1.y = pack2(b1a.z, b1a.w);
      w1.z = pack2(b1b.x, b1b.y); w1.w = pack2(b1b.z, b1b.w);
      *(uint4*)bdst0 = w0;
      *(uint4*)bdst1 = w1;
      __syncthreads();
      bf16x8 af[4], bfr[4];
#pragma unroll
      for (int mi = 0; mi < 4; ++mi)
        af[mi] = *(const bf16x8*)&As[(wm * 64 + mi * 16 + c16) * LDSTR + quad * 8];
#pragma unroll
      for (int ni = 0; ni < 4; ++ni)
        bfr[ni] = *(const bf16x8*)&Bs[(wn * 64 + ni * 16 + c16) * LDSTR + quad * 8];
#pragma unroll
      for (int mi = 0; mi < 4; ++mi)
#pragma unroll
        for (int ni = 0; ni < 4; ++ni)
          acc[mi][ni] = __builtin_amdgcn_mfma_f32_16x16x32_bf16(
              af[mi], bfr[ni], acc[mi][ni], 0, 0, 0);
    }

    msum[arow * 4 + akc] = ss0;
    msum[(arow + 64) * 4 + akc] = ss1;
    __syncthreads();
    if (tid < BN)
      colscale[tid] = (1.0f + 0.3f * imp[n0g + tid]) /
                      sqrtf(msum[tid * 4] + msum[tid * 4 + 1] +
                            msum[tid * 4 + 2] + msum[tid * 4 + 3]);
    __syncthreads();

    float scl[4];
    int gcol[4];
#pragma unroll
    for (int ni = 0; ni < 4; ++ni) {
      scl[ni] = colscale[wn * 64 + ni * 16 + c16];
      gcol[ni] = n0g + wn * 64 + ni * 16 + c16;
    }
#pragma unroll
    for (int mi = 0; mi < 4; ++mi)
#pragma unroll
      for (int ni = 0; ni < 4; ++ni)
#pragma unroll
        for (int reg = 0; reg < 4; ++reg)
          acc[mi][ni][reg] *= qnl[mi * 4 + reg] * scl[ni];

    unsigned long long consumed = 0ull;
    for (;;) {
      float cutl[16];
#pragma unroll
      for (int ii = 0; ii < 16; ++ii)
        cutl[ii] = cutoff[wm * 64 + (ii >> 2) * 16 + quad * 4 + (ii & 3)];
#pragma unroll
      for (int mi = 0; mi < 4; ++mi)
#pragma unroll
        for (int reg = 0; reg < 4; ++reg) {
          const int r = wm * 64 + mi * 16 + quad * 4 + reg;
          const float cl = cutl[mi * 4 + reg];
#pragma unroll
          for (int ni = 0; ni < 4; ++ni) {
            const int bit = mi * 16 + ni * 4 + reg;
            const float v = acc[mi][ni][reg];
            if (!((consumed >> bit) & 1ull) && v > cl) {
              int pos = atomicAdd(&cnt[r], 1);
              if (pos < CAP) {
                cbv[r * CAP + pos] = v;
                cbi[r * CAP + pos] = gcol[ni];
                consumed |= 1ull << bit;
              }
            }
          }
        }
      __syncthreads();
      if (tid < BM) {
        const int r = tid;
        const int m = cnt[r];
        const int take = m < CAP ? m : CAP;
        for (int c = 0; c < take; ++c) {
          const float v = cbv[r * CAP + c];
          const int id = cbi[r * CAP + c];
          if (v > topv[r][TOPK - 1]) {
            int j = TOPK - 1;
            while (j > 0 && topv[r][j - 1] < v) {
              topv[r][j] = topv[r][j - 1];
              topi[r][j] = topi[r][j - 1];
              --j;
            }
            topv[r][j] = v;
            topi[r][j] = id;
          }
        }
        cutoff[r] = topv[r][TOPK - 1];
        if (m > CAP) again = 1;
        cnt[r] = 0;
      }
      __syncthreads();
      const int more = again;
      __syncthreads();
      if (tid == 0) again = 0;
      if (!more) break;
    }
  }

  for (int e = tid; e < BM * TOPK; e += 256) {
    const int r = e >> 4, j = e & 15;
    const size_t o = ((size_t)(bbase + r) * CHUNKS + chunk) * TOPK + j;
    part_v[o] = topv[r][j];
    part_i[o] = topi[r][j];
  }
}

// ---------------------------------------------------------------------------
// final: merge partials -> top-32 approx -> exact fp32 rescore -> top-16 + gather
#define CAND (CHUNKS * TOPK)  // 2048
__global__ __launch_bounds__(256) void final_kernel(
    const float* __restrict__ part_v, const int* __restrict__ part_i,
    const float* __restrict__ mem, const float* __restrict__ query,
    const float* __restrict__ imp, const float* __restrict__ inv_qn,
    float* __restrict__ out) {
  __shared__ float cv[CAND];
  __shared__ int ci[CAND];
  __shared__ float q_s[DIM];
  __shared__ float rv[4];
  __shared__ int rp[4];
  __shared__ float exv[RESCORE];
  __shared__ int exi[RESCORE];
  __shared__ float selv[TOPK];
  __shared__ int seli[TOPK];
  const int b = blockIdx.x, tid = threadIdx.x;
  const int lane = tid & 63, wid = tid >> 6;
  const size_t base = (size_t)b * CAND;
  for (int e = tid; e < CAND; e += 256) {
    cv[e] = part_v[base + e];
    ci[e] = part_i[base + e];
  }
  q_s[tid] = query[(size_t)b * DIM + tid];
  q_s[tid + 256] = query[(size_t)b * DIM + 256 + tid];
  __syncthreads();

  for (int j = 0; j < RESCORE; ++j) {
    float best = NEG_INF;
    int bp = 0;
    for (int e = tid; e < CAND; e += 256)
      if (cv[e] > best) { best = cv[e]; bp = e; }
#pragma unroll
    for (int off = 32; off; off >>= 1) {
      float ov = __shfl_down(best, off);
      int op = __shfl_down(bp, off);
      if (ov > best) { best = ov; bp = op; }
    }
    if (lane == 0) { rv[wid] = best; rp[wid] = bp; }
    __syncthreads();
    if (tid == 0) {
      float bb = rv[0];
      int pp = rp[0];
      for (int w = 1; w < 4; ++w)
        if (rv[w] > bb) { bb = rv[w]; pp = rp[w]; }
      exi[j] = ci[pp];
      cv[pp] = NEG_INF;
    }
    __syncthreads();
  }

  const float iq = inv_qn[b];
  for (int jj = wid; jj < RESCORE; jj += 4) {
    const int idx = exi[jj];
    const float4* mr = (const float4*)(mem + (size_t)idx * DIM);
    float4 m0 = mr[lane * 2], m1 = mr[lane * 2 + 1];
    float4 q0 = *(const float4*)&q_s[lane * 8];
    float4 q1 = *(const float4*)&q_s[lane * 8 + 4];
    float dt = m0.x * q0.x + m0.y * q0.y + m0.z * q0.z + m0.w * q0.w +
               m1.x * q1.x + m1.y * q1.y + m1.z * q1.z + m1.w * q1.w;
    float mm = m0.x * m0.x + m0.y * m0.y + m0.z * m0.z + m0.w * m0.w +
               m1.x * m1.x + m1.y * m1.y + m1.z * m1.z + m1.w * m1.w;
#pragma unroll
    for (int off = 32; off; off >>= 1) {
      dt += __shfl_down(dt, off);
      mm += __shfl_down(mm, off);
    }
    if (lane == 0)
      exv[jj] = dt * iq * (1.0f + 0.3f * imp[idx]) / sqrtf(mm);
  }
  __syncthreads();

  if (tid == 0) {
    u32 used = 0;
    for (int j = 0; j < TOPK; ++j) {
      float bb = NEG_INF;
      int pp = -1;
      for (int c = 0; c < RESCORE; ++c) {
        if ((used >> c) & 1u) continue;
        const float v = exv[c];
        if (v > bb || (pp >= 0 && v == bb && exi[c] < exi[pp])) { bb = v; pp = c; }
      }
      used |= 1u << pp;
      selv[j] = bb;
      seli[j] = exi[pp];
    }
  }
  __syncthreads();
  if (tid < TOPK) out[(size_t)b * TOPK + tid] = selv[tid];
  for (int e = tid; e < TOPK * (DIM / 4); e += 256) {
    const int j = e >> 7, t = e & 127;
    const float4* src = (const float4*)(mem + (size_t)seli[j] * DIM);
    float4* dst = (float4*)(out + (size_t)BQ * TOPK + ((size_t)b * TOPK + j) * DIM);
    dst[t] = src[t];
  }
}

// ---------------------------------------------------------------------------
extern "C" void kernel_launch(void* const* d_in, const int* in_sizes, int n_in,
                              void* d_out, int out_size, void* d_ws, size_t ws_size,
                              hipStream_t stream) {
  const float* query = (const float*)d_in[0];
  const float* mem = (const float*)d_in[1];
  const float* imp = (const float*)d_in[2];
  float* out = (float*)d_out;

  // ws layout: inv_qn[512] f32 | qb[512*512] bf16 | part_v | part_i |
  //            colscale[N] f32 | membf[N*512] bf16
  char* ws = (char*)d_ws;
  float* inv_qn = (float*)ws;
  u16* qb = (u16*)(ws + 2048);
  float* part_v = (float*)(ws + 2048 + (size_t)BQ * DIM * 2);
  int* part_i = (int*)((char*)part_v + (size_t)BQ * CHUNKS * TOPK * 4);
  char* extra = (char*)part_i + (size_t)BQ * CHUNKS * TOPK * 4;
  const size_t used = (size_t)(extra - ws);
  const size_t fast_need =
      used + (size_t)NMEM * 4 + (size_t)NMEM * DIM * 2;  // ~137.5 MB

  hipLaunchKernelGGL(prep_kernel, dim3(BQ / 4), dim3(256), 0, stream,
                     query, inv_qn, qb);
  if (ws_size >= fast_need) {
    float* colscale = (float*)extra;
    u16* membf = (u16*)(extra + (size_t)NMEM * 4);
    hipLaunchKernelGGL(convert_kernel, dim3(NMEM / 4), dim3(256), 0, stream,
                       mem, imp, membf, colscale);
    hipLaunchKernelGGL(main_fast, dim3(BTILES * CHUNKS), dim3(256), 0, stream,
                       qb, membf, colscale, inv_qn, part_v, part_i);
  } else {
    hipLaunchKernelGGL(main_kernel, dim3(BTILES * CHUNKS), dim3(256), 0, stream,
                       qb, mem, imp, inv_qn, part_v, part_i);
  }
  hipLaunchKernelGGL(final_kernel, dim3(BQ), dim3(256), 0, stream,
                     part_v, part_i, mem, query, imp, inv_qn, out);
}